// Round 9
// baseline (276.452 us; speedup 1.0000x reference)
//
#include <hip/hip_runtime.h>
#include <hip/hip_bf16.h>

#define MB_ROWS  8192            // 16 * 512
#define N_LINES  12
#define SCALE    (0.01f / 512.0f)
#define FL_CONST 170.0f          // PROBE_CTS * FL_RATIO * SA_ADJ * SA_THETA
#define EPLANE   (MB_ROWS * 512) // elements per elem-plane of conc
#define WS_NEED  (5ull * (unsigned long long)EPLANE * 2ull)

typedef _Float16 half_t;

// ---------------- K1: rotation (scattered part), 32x32 output tiles ----------
// Stage the tile's source bbox (<=48 rows x <=49 cols, any theta) for all 5
// elems into LDS with COALESCED global reads, then bilinear-gather from LDS
// and write conc as fp16, coalesced, to workspace.
__global__ __launch_bounds__(256) void rotate_kernel(
    const float* __restrict__ xp,       // (5, 16, 512, 512)
    const float* __restrict__ theta_p,  // (1,)
    half_t*      __restrict__ conc16)   // (5, 8192, 512)
{
    const int bid = blockIdx.x;
    const int tx = bid & 15;
    const int ty = (bid >> 4) & 15;
    const int c  = bid >> 8;
    const int s0   = tx << 5;
    const int row0 = ty << 5;
    const int tid  = threadIdx.x;

    const float theta = theta_p[0];
    const float cs = cosf(theta);
    const float sn = sinf(theta);

    // ---- bbox from the 4 corners of the 32x32 output patch ----
    const float gxa = (2.0f * (float)s0          + 1.0f) * (1.0f / 512.0f) - 1.0f;
    const float gxb = (2.0f * (float)(s0 + 31)   + 1.0f) * (1.0f / 512.0f) - 1.0f;
    const float gya = (2.0f * (float)row0        + 1.0f) * (1.0f / 512.0f) - 1.0f;
    const float gyb = (2.0f * (float)(row0 + 31) + 1.0f) * (1.0f / 512.0f) - 1.0f;

    const float xi00 = cs * gxa - sn * gya, xi01 = cs * gxa - sn * gyb;
    const float xi10 = cs * gxb - sn * gya, xi11 = cs * gxb - sn * gyb;
    const float yi00 = sn * gxa + cs * gya, yi01 = sn * gxa + cs * gyb;
    const float yi10 = sn * gxb + cs * gya, yi11 = sn * gxb + cs * gyb;

    const float xmn = fminf(fminf(xi00, xi01), fminf(xi10, xi11));
    const float xmx = fmaxf(fmaxf(xi00, xi01), fmaxf(xi10, xi11));
    const float ymn = fminf(fminf(yi00, yi01), fminf(yi10, yi11));
    const float ymx = fmaxf(fmaxf(yi00, yi01), fmaxf(yi10, yi11));

    const float ixmn = fminf(fmaxf(((xmn + 1.0f) * 512.0f - 1.0f) * 0.5f, 0.0f), 511.0f);
    const float ixmx = fminf(fmaxf(((xmx + 1.0f) * 512.0f - 1.0f) * 0.5f, 0.0f), 511.0f);
    const float iymn = fminf(fmaxf(((ymn + 1.0f) * 512.0f - 1.0f) * 0.5f, 0.0f), 511.0f);
    const float iymx = fminf(fmaxf(((ymx + 1.0f) * 512.0f - 1.0f) * 0.5f, 0.0f), 511.0f);

    const int bbx0 = (int)floorf(ixmn);
    const int bbx1 = min((int)floorf(ixmx) + 2, 511);
    const int bby0 = (int)floorf(iymn);
    const int bby1 = min((int)floorf(iymx) + 2, 511);
    int W = bbx1 - bbx0 + 1;   // <= 47 for any theta (31*sqrt2 + 3)
    int H = bby1 - bby0 + 1;   // <= 47
    if (W > 49) W = 49;        // defensive (LDS row stride)
    if (H > 48) H = 48;

    const size_t estride = (size_t)16 * 512 * 512;
    const float* base = xp + (size_t)c * (512 * 512);

    __shared__ float tiles[5][48 * 49];   // 47040 B

    // ---- stage bbox, coalesced ----
    const int span = H << 6;              // H rows x 64-lane segments
#pragma unroll
    for (int e = 0; e < 5; ++e) {
        const float* plane = base + (size_t)e * estride;
        for (int idx = tid; idx < span; idx += 256) {
            const int yy = idx >> 6;
            const int xx = idx & 63;
            if (xx < W) tiles[e][yy * 49 + xx] = plane[(bby0 + yy) * 512 + bbx0 + xx];
        }
    }
    __syncthreads();

    // ---- gather from LDS, write conc fp16 coalesced ----
    const int sx = tid & 31;          // sample within tile
    const int ry = tid >> 5;          // row group base (0..7)
    const int s  = s0 + sx;
    const float gx = (2.0f * (float)s + 1.0f) * (1.0f / 512.0f) - 1.0f;

#pragma unroll
    for (int q = 0; q < 4; ++q) {
        const int row = row0 + ry + (q << 3);
        const float gy = (2.0f * (float)row + 1.0f) * (1.0f / 512.0f) - 1.0f;

        const float x_in = cs * gx - sn * gy;
        const float y_in = sn * gx + cs * gy;
        float ix = ((x_in + 1.0f) * 512.0f - 1.0f) * 0.5f;
        float iy = ((y_in + 1.0f) * 512.0f - 1.0f) * 0.5f;
        ix = fminf(fmaxf(ix, 0.0f), 511.0f);
        iy = fminf(fmaxf(iy, 0.0f), 511.0f);

        const float x0f = floorf(ix);
        const float y0f = floorf(iy);
        const float wx = ix - x0f;
        const float wy = iy - y0f;
        const int x0 = (int)x0f;
        const int y0 = (int)y0f;
        const int x1 = min(x0 + 1, 511);
        const int y1 = min(y0 + 1, 511);

        const float w00 = (1.0f - wx) * (1.0f - wy);
        const float w01 = wx * (1.0f - wy);
        const float w10 = (1.0f - wx) * wy;
        const float w11 = wx * wy;

        const int o00 = (y0 - bby0) * 49 + (x0 - bbx0);
        const int o01 = (y0 - bby0) * 49 + (x1 - bbx0);
        const int o10 = (y1 - bby0) * 49 + (x0 - bbx0);
        const int o11 = (y1 - bby0) * 49 + (x1 - bbx0);

        const size_t ob = (size_t)(c * 512 + row) * 512 + s;
#pragma unroll
        for (int e = 0; e < 5; ++e) {
            const float* tp = tiles[e];
            const float v = w00 * tp[o00] + w01 * tp[o01]
                          + w10 * tp[o10] + w11 * tp[o11];
            conc16[(size_t)e * EPLANE + ob] = (half_t)v;
        }
    }
}

// ---------------- K2: per-row scan + exp + fluorescence (coalesced) ---------
// One wave per output row; lane L holds samples [8L, 8L+8). Fully wave-local.
__global__ __launch_bounds__(512) void scan_fl_kernel(
    const half_t* __restrict__ conc16,  // (5, 8192, 512)
    const float*  __restrict__ attCS,   // (5,)
    const float*  __restrict__ dfl,     // (12,)
    const int*    __restrict__ lidx,    // (12,)
    float*        __restrict__ out)     // fl (12*8192) ++ trans (8192)
{
    const int tid  = threadIdx.x;
    const int lane = tid & 63;
    const int w    = tid >> 6;
    const int b    = blockIdx.x * 8 + w;   // output row 0..8191

    union Ld { uint4 u; half_t h[8]; };
    Ld ld[5];
#pragma unroll
    for (int e = 0; e < 5; ++e) {
        ld[e].u = *(const uint4*)(conc16 + (size_t)e * EPLANE + (size_t)b * 512 + lane * 8);
    }

    const float a[5] = { attCS[0], attCS[1], attCS[2], attCS[3], attCS[4] };

    // per-sample lac + in-lane inclusive prefix
    float p[8];
    float run = 0.0f;
#pragma unroll
    for (int j = 0; j < 8; ++j) {
        float lac = a[0] * (float)ld[0].h[j];
        lac = fmaf(a[1], (float)ld[1].h[j], lac);
        lac = fmaf(a[2], (float)ld[2].h[j], lac);
        lac = fmaf(a[3], (float)ld[3].h[j], lac);
        lac = fmaf(a[4], (float)ld[4].h[j], lac);
        run += lac;
        p[j] = run;          // inclusive prefix within lane
    }

    // wave-scan of lane totals
    float v = run;
#pragma unroll
    for (int off = 1; off < 64; off <<= 1) {
        float n = __shfl_up(v, off, 64);
        if (lane >= off) v += n;
    }
    const float lane_excl = v - run;          // sum of lanes < lane
    const float row_tot   = __shfl(v, 63, 64);

    // attenuation + fluorescence partials
    float se0 = 0.f, se1 = 0.f, se2 = 0.f, se3 = 0.f, se4 = 0.f;
#pragma unroll
    for (int j = 0; j < 8; ++j) {
        const float excl = lane_excl + p[j] - (a[0] * (float)ld[0].h[j]
                         + a[1] * (float)ld[1].h[j] + a[2] * (float)ld[2].h[j]
                         + a[3] * (float)ld[3].h[j] + a[4] * (float)ld[4].h[j]);
        const float att = __expf(-excl * SCALE);
        se0 = fmaf(att, (float)ld[0].h[j], se0);
        se1 = fmaf(att, (float)ld[1].h[j], se1);
        se2 = fmaf(att, (float)ld[2].h[j], se2);
        se3 = fmaf(att, (float)ld[3].h[j], se3);
        se4 = fmaf(att, (float)ld[4].h[j], se4);
    }

#pragma unroll
    for (int off = 32; off > 0; off >>= 1) {
        se0 += __shfl_down(se0, off, 64);
        se1 += __shfl_down(se1, off, 64);
        se2 += __shfl_down(se2, off, 64);
        se3 += __shfl_down(se3, off, 64);
        se4 += __shfl_down(se4, off, 64);
    }
    const float S0 = __shfl(se0, 0, 64);
    const float S1 = __shfl(se1, 0, 64);
    const float S2 = __shfl(se2, 0, 64);
    const float S3 = __shfl(se3, 0, 64);
    const float S4 = __shfl(se4, 0, 64);

    if (lane == 0) {
        out[(size_t)N_LINES * MB_ROWS + b] = row_tot * SCALE;
    }
    if (lane < N_LINES) {
        const int li = lidx[lane];
        float Ssel = S0;
        Ssel = (li == 1) ? S1 : Ssel;
        Ssel = (li == 2) ? S2 : Ssel;
        Ssel = (li == 3) ? S3 : Ssel;
        Ssel = (li == 4) ? S4 : Ssel;
        out[(size_t)lane * MB_ROWS + b] = FL_CONST * dfl[lane] * Ssel;
    }
}

// ---------------- Fallback: R8 fused kernel (used if ws too small) ----------
struct __attribute__((packed, aligned(4))) F2 { float x, y; };

__global__ __launch_bounds__(512) void fused_fl_kernel(
    const float* __restrict__ xp,
    const float* __restrict__ attCS,
    const float* __restrict__ dfl,
    const float* __restrict__ theta_p,
    const int*   __restrict__ lidx,
    float*       __restrict__ out)
{
    const int bid = blockIdx.x;
    const int t   = bid >> 3;
    const int c   = (bid & 7) + 8 * (t >> 6);
    const int g   = t & 63;
    const int irow0 = g << 3;

    const int tid  = threadIdx.x;
    const int r    = tid & 7;
    const int sc   = tid >> 3;
    const int lane = tid & 63;
    const int w    = tid >> 6;

    const float theta = theta_p[0];
    const float cs = cosf(theta);
    const float sn = sinf(theta);

    const float gyr = (2.0f * (float)(irow0 + r) + 1.0f) * (1.0f / 512.0f) - 1.0f;

    const size_t estride = (size_t)16 * 512 * 512;
    const float* base = xp + (size_t)c * (512 * 512);

    const float a0 = attCS[0], a1 = attCS[1], a2 = attCS[2], a3 = attCS[3], a4 = attCS[4];

    __shared__ float s_x[2][6][8][72];

    float se0 = 0.f, se1 = 0.f, se2 = 0.f, se3 = 0.f, se4 = 0.f;
    float carry = 0.f;

    for (int k = 0; k < 8; ++k) {
        const int buf = k & 1;
        {
            const int s = sc + (k << 6);
            const float gx = (2.0f * (float)s + 1.0f) * (1.0f / 512.0f) - 1.0f;
            const float x_in = cs * gx - sn * gyr;
            const float y_in = sn * gx + cs * gyr;
            float ix = ((x_in + 1.0f) * 512.0f - 1.0f) * 0.5f;
            float iy = ((y_in + 1.0f) * 512.0f - 1.0f) * 0.5f;
            ix = fminf(fmaxf(ix, 0.0f), 511.0f);
            iy = fminf(fmaxf(iy, 0.0f), 511.0f);

            const float x0f = floorf(ix);
            const float y0f = floorf(iy);
            const float wx = ix - x0f;
            const float wy = iy - y0f;
            const int x0 = (int)x0f;
            const int y0 = (int)y0f;
            const int y1 = min(y0 + 1, 511);

            const bool edge = (x0 >= 511);
            const int  xL   = edge ? 510 : x0;

            const float w1y0 = wx * (1.0f - wy);
            const float w1y1 = wx * wy;
            const float w0y0 = (1.0f - wx) * (1.0f - wy);
            const float w0y1 = (1.0f - wx) * wy;

            const int oA = y0 * 512 + xL;
            const int oB = y1 * 512 + xL;

            float cv[5];
            const float* p = base;
#pragma unroll
            for (int e = 0; e < 5; ++e) {
                const F2 pa = *(const F2*)(p + oA);
                const F2 pb = *(const F2*)(p + oB);
                const float vA0 = edge ? pa.y : pa.x;
                const float vB0 = edge ? pb.y : pb.x;
                float acc = w0y0 * vA0;
                acc = fmaf(w1y0, pa.y, acc);
                acc = fmaf(w0y1, vB0, acc);
                acc = fmaf(w1y1, pb.y, acc);
                cv[e] = acc;
                p += estride;
            }

            float lac = a0 * cv[0];
            lac = fmaf(a1, cv[1], lac);
            lac = fmaf(a2, cv[2], lac);
            lac = fmaf(a3, cv[3], lac);
            lac = fmaf(a4, cv[4], lac);

            s_x[buf][0][r][sc] = cv[0];
            s_x[buf][1][r][sc] = cv[1];
            s_x[buf][2][r][sc] = cv[2];
            s_x[buf][3][r][sc] = cv[3];
            s_x[buf][4][r][sc] = cv[4];
            s_x[buf][5][r][sc] = lac;
        }

        __syncthreads();

        {
            const float lv = s_x[buf][5][w][lane];
            float v = lv;
#pragma unroll
            for (int off = 1; off < 64; off <<= 1) {
                float n = __shfl_up(v, off, 64);
                if (lane >= off) v += n;
            }
            const float tot  = __shfl(v, 63, 64);
            const float excl = carry + v - lv;
            const float att  = __expf(-excl * SCALE);
            carry += tot;

            se0 = fmaf(att, s_x[buf][0][w][lane], se0);
            se1 = fmaf(att, s_x[buf][1][w][lane], se1);
            se2 = fmaf(att, s_x[buf][2][w][lane], se2);
            se3 = fmaf(att, s_x[buf][3][w][lane], se3);
            se4 = fmaf(att, s_x[buf][4][w][lane], se4);
        }
    }

#pragma unroll
    for (int off = 32; off > 0; off >>= 1) {
        se0 += __shfl_down(se0, off, 64);
        se1 += __shfl_down(se1, off, 64);
        se2 += __shfl_down(se2, off, 64);
        se3 += __shfl_down(se3, off, 64);
        se4 += __shfl_down(se4, off, 64);
    }
    const float S0 = __shfl(se0, 0, 64);
    const float S1 = __shfl(se1, 0, 64);
    const float S2 = __shfl(se2, 0, 64);
    const float S3 = __shfl(se3, 0, 64);
    const float S4 = __shfl(se4, 0, 64);

    const size_t b = (size_t)c * 512 + irow0 + w;
    if (lane == 0) {
        out[(size_t)N_LINES * MB_ROWS + b] = carry * SCALE;
    }
    if (lane < N_LINES) {
        const int li = lidx[lane];
        float Ssel = S0;
        Ssel = (li == 1) ? S1 : Ssel;
        Ssel = (li == 2) ? S2 : Ssel;
        Ssel = (li == 3) ? S3 : Ssel;
        Ssel = (li == 4) ? S4 : Ssel;
        out[(size_t)lane * MB_ROWS + b] = FL_CONST * dfl[lane] * Ssel;
    }
}

extern "C" void kernel_launch(void* const* d_in, const int* in_sizes, int n_in,
                              void* d_out, int out_size, void* d_ws, size_t ws_size,
                              hipStream_t stream) {
    const float* xp    = (const float*)d_in[0];
    const float* attCS = (const float*)d_in[1];
    const float* dfl   = (const float*)d_in[2];
    const float* theta = (const float*)d_in[3];
    const int*   lidx  = (const int*)d_in[4];
    float* out = (float*)d_out;

    if (ws_size >= WS_NEED) {
        half_t* conc16 = (half_t*)d_ws;
        rotate_kernel<<<4096, 256, 0, stream>>>(xp, theta, conc16);
        scan_fl_kernel<<<MB_ROWS / 8, 512, 0, stream>>>(conc16, attCS, dfl, lidx, out);
    } else {
        fused_fl_kernel<<<MB_ROWS / 8, 512, 0, stream>>>(xp, attCS, dfl, theta, lidx, out);
    }
}

// Round 10
// 158.984 us; speedup vs baseline: 1.7389x; 1.7389x over previous
//
#include <hip/hip_runtime.h>
#include <hip/hip_bf16.h>

#define MB_ROWS  8192            // 16 * 512
#define N_LINES  12
#define SCALE    (0.01f / 512.0f)
#define FL_CONST 170.0f          // PROBE_CTS * FL_RATIO * SA_ADJ * SA_THETA

// 8-byte (4B-aligned) load carrying both x-taps of one source row.
struct __attribute__((packed, aligned(4))) F2 { float x, y; };

// Block = 8 output rows (one channel) x 512 samples. 8 waves; wave w owns
// SEGMENT w (64 samples) of all 8 rows, processed as 8 chunks of 8 samples.
// Lane = (r = lane>>3, j = lane&7): an 8x8 output patch per gather instr
// (same TA footprint as R8). The row scan is a SEGMENTED 8-wide shfl scan
// with an in-register carry -> cv[e] and att live in the same lane: zero
// LDS and zero barriers in the main loop. Segments are stitched at the end
// via exp(-(P+q)) = exp(-P)*exp(-q): one 1.5KB LDS exchange + 1 barrier +
// a combine in wave 0.
__global__ __launch_bounds__(512, 4) void fused_fl_kernel(
    const float* __restrict__ xp,       // (5, 16, 512, 512)
    const float* __restrict__ attCS,    // (5,)
    const float* __restrict__ dfl,      // (12,)
    const float* __restrict__ theta_p,  // (1,)
    const int*   __restrict__ lidx,     // (12,)
    float*       __restrict__ out)      // fl_sig (12*8192) ++ transmission (8192)
{
    const int bid = blockIdx.x;
    const int t   = bid >> 3;
    const int c   = (bid & 7) + 8 * (t >> 6);   // channel, XCD-affine
    const int g   = t & 63;
    const int irow0 = g << 3;

    const int tid  = threadIdx.x;
    const int lane = tid & 63;
    const int w    = tid >> 6;   // segment 0..7 (samples w*64 .. w*64+63)
    const int j    = lane & 7;   // sample within chunk
    const int r    = lane >> 3;  // row within group

    const float theta = theta_p[0];
    const float cs = cosf(theta);
    const float sn = sinf(theta);

    const float gyr = (2.0f * (float)(irow0 + r) + 1.0f) * (1.0f / 512.0f) - 1.0f;

    const size_t estride = (size_t)16 * 512 * 512;
    const float* base = xp + (size_t)c * (512 * 512);

    const float a0 = attCS[0], a1 = attCS[1], a2 = attCS[2], a3 = attCS[3], a4 = attCS[4];

    __shared__ float s_seg[8][8][6];   // [seg][row][A, S0..S4] = 1536 B

    float se0 = 0.f, se1 = 0.f, se2 = 0.f, se3 = 0.f, se4 = 0.f;
    float carry = 0.f;                 // segment-local running row-sum

    for (int k = 0; k < 8; ++k) {
        // ---- gather: sample s of row irow0+r (8x8 patch per instruction) ----
        const int s = (w << 6) + (k << 3) + j;
        const float gx = (2.0f * (float)s + 1.0f) * (1.0f / 512.0f) - 1.0f;
        const float x_in = cs * gx - sn * gyr;
        const float y_in = sn * gx + cs * gyr;
        float ix = ((x_in + 1.0f) * 512.0f - 1.0f) * 0.5f;
        float iy = ((y_in + 1.0f) * 512.0f - 1.0f) * 0.5f;
        ix = fminf(fmaxf(ix, 0.0f), 511.0f);
        iy = fminf(fmaxf(iy, 0.0f), 511.0f);

        const float x0f = floorf(ix);
        const float y0f = floorf(iy);
        const float wx = ix - x0f;
        const float wy = iy - y0f;
        const int x0 = (int)x0f;
        const int y0 = (int)y0f;
        const int y1 = min(y0 + 1, 511);

        const bool edge = (x0 >= 511);
        const int  xL   = edge ? 510 : x0;

        const float w0y0 = (1.0f - wx) * (1.0f - wy);
        const float w1y0 = wx * (1.0f - wy);
        const float w0y1 = (1.0f - wx) * wy;
        const float w1y1 = wx * wy;

        const int oA = y0 * 512 + xL;
        const int oB = y1 * 512 + xL;

        float cv0, cv1, cv2, cv3, cv4;
        {
            const float* p = base;
            F2 pa, pb;
            pa = *(const F2*)(p + oA); pb = *(const F2*)(p + oB);
            cv0 = w0y0 * (edge ? pa.y : pa.x) + w1y0 * pa.y
                + w0y1 * (edge ? pb.y : pb.x) + w1y1 * pb.y;
            p += estride;
            pa = *(const F2*)(p + oA); pb = *(const F2*)(p + oB);
            cv1 = w0y0 * (edge ? pa.y : pa.x) + w1y0 * pa.y
                + w0y1 * (edge ? pb.y : pb.x) + w1y1 * pb.y;
            p += estride;
            pa = *(const F2*)(p + oA); pb = *(const F2*)(p + oB);
            cv2 = w0y0 * (edge ? pa.y : pa.x) + w1y0 * pa.y
                + w0y1 * (edge ? pb.y : pb.x) + w1y1 * pb.y;
            p += estride;
            pa = *(const F2*)(p + oA); pb = *(const F2*)(p + oB);
            cv3 = w0y0 * (edge ? pa.y : pa.x) + w1y0 * pa.y
                + w0y1 * (edge ? pb.y : pb.x) + w1y1 * pb.y;
            p += estride;
            pa = *(const F2*)(p + oA); pb = *(const F2*)(p + oB);
            cv4 = w0y0 * (edge ? pa.y : pa.x) + w1y0 * pa.y
                + w0y1 * (edge ? pb.y : pb.x) + w1y1 * pb.y;
        }

        float lac = a0 * cv0;
        lac = fmaf(a1, cv1, lac);
        lac = fmaf(a2, cv2, lac);
        lac = fmaf(a3, cv3, lac);
        lac = fmaf(a4, cv4, lac);

        // ---- segmented (8-wide) inclusive scan over j ----
        float v = lac;
#pragma unroll
        for (int off = 1; off < 8; off <<= 1) {
            float n = __shfl_up(v, off, 64);
            if (j >= off) v += n;
        }
        const float tot = __shfl(v, lane | 7, 64);   // row-chunk total -> whole group
        const float att = __expf(-(carry + v - lac) * SCALE);
        carry += tot;

        se0 = fmaf(att, cv0, se0);
        se1 = fmaf(att, cv1, se1);
        se2 = fmaf(att, cv2, se2);
        se3 = fmaf(att, cv3, se3);
        se4 = fmaf(att, cv4, se4);
    }

    // ---- in-group reduce of se over j (segment partials) ----
#pragma unroll
    for (int off = 1; off < 8; off <<= 1) {
        se0 += __shfl_xor(se0, off, 64);
        se1 += __shfl_xor(se1, off, 64);
        se2 += __shfl_xor(se2, off, 64);
        se3 += __shfl_xor(se3, off, 64);
        se4 += __shfl_xor(se4, off, 64);
    }

    if (j == 0) {
        s_seg[w][r][0] = carry;   // segment attenuation-sum A
        s_seg[w][r][1] = se0;
        s_seg[w][r][2] = se1;
        s_seg[w][r][3] = se2;
        s_seg[w][r][4] = se3;
        s_seg[w][r][5] = se4;
    }
    __syncthreads();

    // ---- combine (wave 0): lane = r*8 + seg ----
    if (w == 0) {
        const int seg = j;
        const float A = s_seg[seg][r][0];

        float v = A;   // inclusive prefix of A over segments
#pragma unroll
        for (int off = 1; off < 8; off <<= 1) {
            float n = __shfl_up(v, off, 64);
            if (seg >= off) v += n;
        }
        const float f = __expf(-(v - A) * SCALE);   // exp(-prefix_before_seg)

        float S0 = f * s_seg[seg][r][1];
        float S1 = f * s_seg[seg][r][2];
        float S2 = f * s_seg[seg][r][3];
        float S3 = f * s_seg[seg][r][4];
        float S4 = f * s_seg[seg][r][5];
#pragma unroll
        for (int off = 1; off < 8; off <<= 1) {
            S0 += __shfl_xor(S0, off, 64);
            S1 += __shfl_xor(S1, off, 64);
            S2 += __shfl_xor(S2, off, 64);
            S3 += __shfl_xor(S3, off, 64);
            S4 += __shfl_xor(S4, off, 64);
        }

        const float rowtot = __shfl(v, lane | 7, 64);
        const size_t b = (size_t)c * 512 + irow0 + r;

        if (seg == 7) {
            out[(size_t)N_LINES * MB_ROWS + b] = rowtot * SCALE;
        }
        {
            const int l = seg;                 // lines 0..7
            const int li = lidx[l];
            float Ssel = S0;
            Ssel = (li == 1) ? S1 : Ssel;
            Ssel = (li == 2) ? S2 : Ssel;
            Ssel = (li == 3) ? S3 : Ssel;
            Ssel = (li == 4) ? S4 : Ssel;
            out[(size_t)l * MB_ROWS + b] = FL_CONST * dfl[l] * Ssel;
        }
        if (seg < 4) {                         // lines 8..11
            const int l = seg + 8;
            const int li = lidx[l];
            float Ssel = S0;
            Ssel = (li == 1) ? S1 : Ssel;
            Ssel = (li == 2) ? S2 : Ssel;
            Ssel = (li == 3) ? S3 : Ssel;
            Ssel = (li == 4) ? S4 : Ssel;
            out[(size_t)l * MB_ROWS + b] = FL_CONST * dfl[l] * Ssel;
        }
    }
}

extern "C" void kernel_launch(void* const* d_in, const int* in_sizes, int n_in,
                              void* d_out, int out_size, void* d_ws, size_t ws_size,
                              hipStream_t stream) {
    const float* xp    = (const float*)d_in[0];
    const float* attCS = (const float*)d_in[1];
    const float* dfl   = (const float*)d_in[2];
    const float* theta = (const float*)d_in[3];
    const int*   lidx  = (const int*)d_in[4];
    float* out = (float*)d_out;

    fused_fl_kernel<<<MB_ROWS / 8, 512, 0, stream>>>(xp, attCS, dfl, theta, lidx, out);
}